// Round 1
// baseline (64.895 us; speedup 1.0000x reference)
//
#include <hip/hip_runtime.h>

// SRTM (simplified reference tissue model) per-voxel kinetic evaluation.
//
// Reference math, per voxel l:
//   A = -k1/(1+k2); B = k1*(1 - k0/(1+k2)); d = exp(A*dt), dt = 1/60
//   f[i] = clip(lerp(ref_tac onto fine grid), 0)   (shared across voxels)
//   c_i = d*c_{i-1} + f[i]*dt  (c_{-1}=0), sampled at i = 60*frame
//   y[frame, l] = ref_tac[frame]*k0 + B*c_{60*frame}
//
// Optimization: f is piecewise-LINEAR on each 60-step segment (frames are at
// integer minutes, fine grid is 1/60 min), and the recursion is linear, so a
// whole segment collapses to:
//   c_{60(j+1)} = d^60 * c_{60j} + dt*( r_j * P + (s_j/60) * Q )
// with P = sum_{m=0..59} d^m, Q = sum_{m=0..59} (60-m) d^m, s_j = r_{j+1}-r_j.
// P, Q, d^60 are per-voxel constants (60-iteration warm-up loop, all-positive
// accumulation -> numerically robust). Serial chain: 3601 steps -> 61 steps.
// clip(,0) is a no-op: ref_tac >= 0 and lerp of nonnegatives is nonnegative.

__global__ __launch_bounds__(64) void srtm_kernel(
    const float* __restrict__ ref_tac,  // [T]
    const float* __restrict__ k,        // [3, L]
    float* __restrict__ y,              // [T, L]
    int T, int L)
{
    int v = blockIdx.x * blockDim.x + threadIdx.x;
    if (v >= L) return;

    const float dt = 1.0f / 60.0f;

    float k0 = k[v];
    float k1 = k[L + v];
    float k2 = k[2 * L + v];

    float inv = 1.0f / (1.0f + k2);
    float A   = -k1 * inv;
    float B   = k1 * (1.0f - k0 * inv);
    float d   = __expf(A * dt);

    // P = sum d^m, Q = sum (60-m) d^m, m = 0..59; dm ends as d^60.
    float p = 0.0f, q = 0.0f, dm = 1.0f, w = 60.0f;
#pragma unroll 6
    for (int m = 0; m < 60; ++m) {
        p += dm;
        q = fmaf(w, dm, q);
        dm *= d;
        w -= 1.0f;
    }
    const float d60 = dm;
    const float U = p * dt;                   // multiplies r_j
    const float V = q * dt * (1.0f / 60.0f);  // multiplies s_j

    // Frame 0: c after the very first fine step = f[0]*dt = r0*dt.
    float r0 = ref_tac[0];
    float c  = r0 * dt;
    y[v] = fmaf(B, c, r0 * k0);

    for (int j = 0; j + 1 < T; ++j) {
        float rj  = ref_tac[j];       // wave-uniform -> scalar load, cached
        float rj1 = ref_tac[j + 1];
        float s   = rj1 - rj;
        float term = fmaf(rj, U, s * V);
        c = fmaf(d60, c, term);
        y[(size_t)(j + 1) * L + v] = fmaf(B, c, rj1 * k0);
    }
}

extern "C" void kernel_launch(void* const* d_in, const int* in_sizes, int n_in,
                              void* d_out, int out_size, void* d_ws, size_t ws_size,
                              hipStream_t stream) {
    // inputs: [0] t (int32 [T]) unused (t == arange(T) minutes),
    //         [1] ref_tac (f32 [T]), [2] k (f32 [3,L]), [3] n_tao (unused)
    const float* ref_tac = (const float*)d_in[1];
    const float* k       = (const float*)d_in[2];
    float* y             = (float*)d_out;

    int T = in_sizes[0];
    int L = in_sizes[2] / 3;

    // 64-thread blocks -> 512 blocks for L=32768: every CU gets work.
    dim3 block(64);
    dim3 grid((L + block.x - 1) / block.x);
    srtm_kernel<<<grid, block, 0, stream>>>(ref_tac, k, y, T, L);
}

// Round 2
// 62.554 us; speedup vs baseline: 1.0374x; 1.0374x over previous
//
#include <hip/hip_runtime.h>

// SRTM (simplified reference tissue model) per-voxel kinetic evaluation.
//
// Reference math, per voxel l:
//   A = -k1/(1+k2); B = k1*(1 - k0/(1+k2)); d = exp(A*dt), dt = 1/60
//   f[i] = clip(lerp(ref_tac onto fine grid), 0)   (shared across voxels)
//   c_i = d*c_{i-1} + f[i]*dt  (c_{-1}=0), sampled at i = 60*frame
//   y[frame, l] = ref_tac[frame]*k0 + B*c_{60*frame}
//
// Segment closed form (f piecewise-linear over each 60-step segment, linear
// recursion): c_{60(j+1)} = d^60 c_{60j} + dt*(r_j*P + (s_j/60)*Q),
// P = sum_{m<60} d^m, Q = sum_{m<60}(60-m)d^m, s_j = r_{j+1}-r_j.
// Serial chain: 3601 -> 61 steps. clip is a no-op (ref_tac >= 0).
//
// Round-2 change: compile-time T (=61) specialization. ref_tac preloaded into
// a fully-unrolled register array so all 61 wave-uniform loads issue upfront
// (one latency, not 61 serialized per-iteration loads), frame loop fully
// unrolled. Only remaining serial chain: 60 dependent FMAs on c.

template <int T>
__global__ __launch_bounds__(64) void srtm_kernel_t(
    const float* __restrict__ ref_tac,  // [T]
    const float* __restrict__ k,        // [3, L]
    float* __restrict__ y,              // [T, L]
    int L)
{
    int v = blockIdx.x * blockDim.x + threadIdx.x;
    if (v >= L) return;

    const float dt = 1.0f / 60.0f;

    float k0 = k[v];
    float k1 = k[L + v];
    float k2 = k[2 * L + v];

    float inv = 1.0f / (1.0f + k2);
    float A   = -k1 * inv;
    float B   = k1 * (1.0f - k0 * inv);
    float d   = __expf(A * dt);

    // P = sum d^m, Q = sum (60-m) d^m, m = 0..59; dm ends as d^60.
    // All-positive accumulation (d in (0,1)) -> numerically robust; avoids
    // the (1-d^60)/(1-d) cancellation (1-d ~ 1e-3 here).
    float p = 0.0f, q = 0.0f, dm = 1.0f, w = 60.0f;
#pragma unroll
    for (int m = 0; m < 60; ++m) {
        p += dm;
        q = fmaf(w, dm, q);
        dm *= d;
        w -= 1.0f;
    }
    const float d60 = dm;
    const float U = p * dt;                   // multiplies r_j
    const float V = q * dt * (1.0f / 60.0f);  // multiplies s_j

    // Preload the whole reference TAC (wave-uniform -> scalar loads, all
    // issued before first use thanks to full unroll).
    float r[T];
#pragma unroll
    for (int j = 0; j < T; ++j) r[j] = ref_tac[j];

    // Frame 0: c after the very first fine step = f[0]*dt.
    float c = r[0] * dt;
    y[v] = fmaf(B, c, r[0] * k0);

#pragma unroll
    for (int j = 0; j + 1 < T; ++j) {
        float s = r[j + 1] - r[j];
        c = fmaf(d60, c, fmaf(r[j], U, s * V));
        y[(size_t)(j + 1) * L + v] = fmaf(B, c, r[j + 1] * k0);
    }
}

// Generic fallback for unexpected T.
__global__ __launch_bounds__(64) void srtm_kernel_g(
    const float* __restrict__ ref_tac,
    const float* __restrict__ k,
    float* __restrict__ y,
    int T, int L)
{
    int v = blockIdx.x * blockDim.x + threadIdx.x;
    if (v >= L) return;

    const float dt = 1.0f / 60.0f;
    float k0 = k[v], k1 = k[L + v], k2 = k[2 * L + v];
    float inv = 1.0f / (1.0f + k2);
    float A = -k1 * inv;
    float B = k1 * (1.0f - k0 * inv);
    float d = __expf(A * dt);

    float p = 0.0f, q = 0.0f, dm = 1.0f, w = 60.0f;
    for (int m = 0; m < 60; ++m) { p += dm; q = fmaf(w, dm, q); dm *= d; w -= 1.0f; }
    const float d60 = dm;
    const float U = p * dt;
    const float V = q * dt * (1.0f / 60.0f);

    float r0 = ref_tac[0];
    float c = r0 * dt;
    y[v] = fmaf(B, c, r0 * k0);
    for (int j = 0; j + 1 < T; ++j) {
        float rj = ref_tac[j], rj1 = ref_tac[j + 1];
        c = fmaf(d60, c, fmaf(rj, U, (rj1 - rj) * V));
        y[(size_t)(j + 1) * L + v] = fmaf(B, c, rj1 * k0);
    }
}

extern "C" void kernel_launch(void* const* d_in, const int* in_sizes, int n_in,
                              void* d_out, int out_size, void* d_ws, size_t ws_size,
                              hipStream_t stream) {
    // inputs: [0] t (int32 [T]) unused (t == arange(T) minutes),
    //         [1] ref_tac (f32 [T]), [2] k (f32 [3,L]), [3] n_tao (unused)
    const float* ref_tac = (const float*)d_in[1];
    const float* k       = (const float*)d_in[2];
    float* y             = (float*)d_out;

    int T = in_sizes[0];
    int L = in_sizes[2] / 3;

    dim3 block(64);
    dim3 grid((L + block.x - 1) / block.x);
    if (T == 61) {
        srtm_kernel_t<61><<<grid, block, 0, stream>>>(ref_tac, k, y, L);
    } else {
        srtm_kernel_g<<<grid, block, 0, stream>>>(ref_tac, k, y, T, L);
    }
}

// Round 3
// 62.255 us; speedup vs baseline: 1.0424x; 1.0048x over previous
//
#include <hip/hip_runtime.h>

// SRTM (simplified reference tissue model) per-voxel kinetic evaluation.
//
// Reference math, per voxel l:
//   A = -k1/(1+k2); B = k1*(1 - k0/(1+k2)); d = exp(A*dt), dt = 1/60
//   f[i] = clip(lerp(ref_tac onto fine grid), 0)   (shared across voxels)
//   c_i = d*c_{i-1} + f[i]*dt  (c_{-1}=0), sampled at i = 60*frame
//   y[frame, l] = ref_tac[frame]*k0 + B*c_{60*frame}
//
// Segment closed form (f piecewise-linear over each 60-step segment, linear
// recursion): c_{60(j+1)} = d^60 c_{60j} + dt*(r_j*P + (s_j/60)*Q),
// P = sum_{m<60} d^m, Q = sum_{m<60}(60-m)d^m, s_j = r_{j+1}-r_j.
// Serial chain: 3601 -> 61 steps. clip is a no-op (ref_tac >= 0).
//
// Round-3 change: 2 voxels per thread. Doubles ILP on the two dependent
// chains (warm-up dm*=d and the 60-frame c-FMA chain), halves store
// instruction count via float2 (8 B/lane, fully coalesced), still one wave
// on every CU (256 blocks x 64 threads for L=32768).

template <int T>
__global__ __launch_bounds__(64) void srtm_kernel_t2(
    const float* __restrict__ ref_tac,  // [T]
    const float* __restrict__ k,        // [3, L]
    float* __restrict__ y,              // [T, L]
    int L)
{
    int tid = blockIdx.x * blockDim.x + threadIdx.x;
    int v0 = tid * 2;
    if (v0 + 1 >= L) return;

    const float dt = 1.0f / 60.0f;

    float2 k0 = *(const float2*)&k[v0];
    float2 k1 = *(const float2*)&k[L + v0];
    float2 k2 = *(const float2*)&k[2 * L + v0];

    float invx = 1.0f / (1.0f + k2.x);
    float invy = 1.0f / (1.0f + k2.y);
    float Bx = k1.x * (1.0f - k0.x * invx);
    float By = k1.y * (1.0f - k0.y * invy);
    float dx = __expf(-k1.x * invx * dt);
    float dy = __expf(-k1.y * invy * dt);

    // P = sum d^m, Q = sum (60-m) d^m, m = 0..59; dm ends as d^60.
    // All-positive accumulation (d in (0,1)) -> robust; avoids the
    // (1-d^60)/(1-d) cancellation (1-d ~ 1e-3 here). Two chains interleave.
    float px = 0.0f, qx = 0.0f, dmx = 1.0f;
    float py = 0.0f, qy = 0.0f, dmy = 1.0f;
    float w = 60.0f;
#pragma unroll
    for (int m = 0; m < 60; ++m) {
        px += dmx;            py += dmy;
        qx = fmaf(w, dmx, qx); qy = fmaf(w, dmy, qy);
        dmx *= dx;            dmy *= dy;
        w -= 1.0f;
    }
    const float d60x = dmx, d60y = dmy;
    const float Ux = px * dt, Uy = py * dt;             // multiplies r_j
    const float Vx = qx * dt * (1.0f / 60.0f);          // multiplies s_j
    const float Vy = qy * dt * (1.0f / 60.0f);

    // Preload reference TAC (wave-uniform -> scalar loads, issued upfront).
    float r[T];
#pragma unroll
    for (int j = 0; j < T; ++j) r[j] = ref_tac[j];

    // Frame 0: c after the very first fine step = f[0]*dt.
    float cx = r[0] * dt;
    float cy = cx;
    *(float2*)&y[v0] = make_float2(fmaf(Bx, cx, r[0] * k0.x),
                                   fmaf(By, cy, r[0] * k0.y));

#pragma unroll
    for (int j = 0; j + 1 < T; ++j) {
        float s = r[j + 1] - r[j];
        cx = fmaf(d60x, cx, fmaf(r[j], Ux, s * Vx));
        cy = fmaf(d60y, cy, fmaf(r[j], Uy, s * Vy));
        *(float2*)&y[(size_t)(j + 1) * L + v0] =
            make_float2(fmaf(Bx, cx, r[j + 1] * k0.x),
                        fmaf(By, cy, r[j + 1] * k0.y));
    }
}

// Generic fallback (any T, any L, 1 voxel/thread).
__global__ __launch_bounds__(64) void srtm_kernel_g(
    const float* __restrict__ ref_tac,
    const float* __restrict__ k,
    float* __restrict__ y,
    int T, int L)
{
    int v = blockIdx.x * blockDim.x + threadIdx.x;
    if (v >= L) return;

    const float dt = 1.0f / 60.0f;
    float k0 = k[v], k1 = k[L + v], k2 = k[2 * L + v];
    float inv = 1.0f / (1.0f + k2);
    float B = k1 * (1.0f - k0 * inv);
    float d = __expf(-k1 * inv * dt);

    float p = 0.0f, q = 0.0f, dm = 1.0f, w = 60.0f;
    for (int m = 0; m < 60; ++m) { p += dm; q = fmaf(w, dm, q); dm *= d; w -= 1.0f; }
    const float d60 = dm;
    const float U = p * dt;
    const float V = q * dt * (1.0f / 60.0f);

    float r0 = ref_tac[0];
    float c = r0 * dt;
    y[v] = fmaf(B, c, r0 * k0);
    for (int j = 0; j + 1 < T; ++j) {
        float rj = ref_tac[j], rj1 = ref_tac[j + 1];
        c = fmaf(d60, c, fmaf(rj, U, (rj1 - rj) * V));
        y[(size_t)(j + 1) * L + v] = fmaf(B, c, rj1 * k0);
    }
}

extern "C" void kernel_launch(void* const* d_in, const int* in_sizes, int n_in,
                              void* d_out, int out_size, void* d_ws, size_t ws_size,
                              hipStream_t stream) {
    // inputs: [0] t (int32 [T]) unused (t == arange(T) minutes),
    //         [1] ref_tac (f32 [T]), [2] k (f32 [3,L]), [3] n_tao (unused)
    const float* ref_tac = (const float*)d_in[1];
    const float* k       = (const float*)d_in[2];
    float* y             = (float*)d_out;

    int T = in_sizes[0];
    int L = in_sizes[2] / 3;

    if (T == 61 && (L & 1) == 0) {
        int threads = L / 2;                      // 16384 -> 256 waves, 1/CU
        dim3 block(64);
        dim3 grid((threads + block.x - 1) / block.x);
        srtm_kernel_t2<61><<<grid, block, 0, stream>>>(ref_tac, k, y, L);
    } else {
        dim3 block(64);
        dim3 grid((L + block.x - 1) / block.x);
        srtm_kernel_g<<<grid, block, 0, stream>>>(ref_tac, k, y, T, L);
    }
}